// Round 1
// baseline (279.252 us; speedup 1.0000x reference)
//
#include <hip/hip_runtime.h>
#include <math.h>

#define BDIM 8
#define NSEQ 4096
#define DDIM 768
#define HDIM 256
#define ROWS 2

// ---------------- kernel 1: column sums over N ----------------
__global__ __launch_bounds__(256)
void colsum_kernel(const float* __restrict__ x, float* __restrict__ csum) {
    int blk = blockIdx.x;
    int nch = blk & 63;            // 64 N-chunks
    int dchunk = (blk >> 6) % 3;   // 3 chunks of 256 d's
    int b = blk / 192;
    int d = dchunk * 256 + threadIdx.x;
    const int nper = NSEQ / 64;    // 64
    int n0 = nch * nper;
    const float* p = x + ((size_t)b * NSEQ + n0) * DDIM + d;
    float acc = 0.f;
    #pragma unroll 8
    for (int i = 0; i < nper; ++i) acc += p[(size_t)i * DDIM];
    atomicAdd(&csum[b * DDIM + d], acc);
}

// ---------------- kernel 2: MLP for delta_W ----------------
__global__ __launch_bounds__(256)
void mlp_kernel(const float* __restrict__ csum,
                const float* __restrict__ w1, const float* __restrict__ b1,
                const float* __restrict__ w2, const float* __restrict__ b2,
                float* __restrict__ dW) {
    int b = blockIdx.x;
    int t = threadIdx.x;
    __shared__ float c[DDIM];
    __shared__ float h[HDIM];
    for (int d = t; d < DDIM; d += 256) c[d] = csum[b * DDIM + d] * (1.0f / NSEQ);
    __syncthreads();
    float acc = b1[t];
    #pragma unroll 4
    for (int d = 0; d < DDIM; ++d) acc = fmaf(c[d], w1[d * HDIM + t], acc);
    // JAX default gelu: tanh approximation
    float x3 = acc * acc * acc;
    float g = 0.5f * acc * (1.0f + tanhf(0.7978845608028654f * (acc + 0.044715f * x3)));
    h[t] = g;
    __syncthreads();
    for (int d = t; d < DDIM; d += 256) {
        float a = b2[d];
        #pragma unroll 4
        for (int j = 0; j < HDIM; ++j) a = fmaf(h[j], w2[j * DDIM + d], a);
        dW[b * DDIM + d] = a;
    }
}

// ---------------- Stockham DIF stage ----------------
// Invariant: before stage, element b of sub-transform sigma lives at src[b*S + sigma].
// Butterfly id in [0, S*M): u = id/S, sigma = id%S.
// Reads src[a*(M*S) + id]; twiddle omega_768^(u*d*S); writes dst[u*R*S + d*S + sigma].
template <int R, int S, int M, bool INV>
__device__ __forceinline__ void fft_stage(
    const float* __restrict__ sre, const float* __restrict__ sim,
    float* __restrict__ dre, float* __restrict__ dim_,
    const float* __restrict__ twr, const float* __restrict__ twi, int lane)
{
    constexpr int NB = S * M;  // butterflies = 768/R = read stride
    #pragma unroll
    for (int it = 0; it < NB / 64; ++it) {
        const int id = lane + 64 * it;
        const int u  = id / S;
        const int sg = id - u * S;
        const int ob = u * R * S + sg;
        if constexpr (R == 4) {
            float x0r = sre[id],          x0i = sim[id];
            float x1r = sre[NB + id],     x1i = sim[NB + id];
            float x2r = sre[2 * NB + id], x2i = sim[2 * NB + id];
            float x3r = sre[3 * NB + id], x3i = sim[3 * NB + id];
            float t0r = x0r + x2r, t0i = x0i + x2i;
            float t1r = x0r - x2r, t1i = x0i - x2i;
            float t2r = x1r + x3r, t2i = x1i + x3i;
            float t3r = x1r - x3r, t3i = x1i - x3i;
            float A0r = t0r + t2r, A0i = t0i + t2i;
            float A2r = t0r - t2r, A2i = t0i - t2i;
            float A1r, A1i, A3r, A3i;
            if constexpr (!INV) {
                A1r = t1r + t3i; A1i = t1i - t3r;   // t1 - i*t3
                A3r = t1r - t3i; A3i = t1i + t3r;   // t1 + i*t3
            } else {
                A1r = t1r - t3i; A1i = t1i + t3r;
                A3r = t1r + t3i; A3i = t1i - t3r;
            }
            if constexpr (M > 1) {
                const int e = u * S;
                float w1r = twr[e],     w1i = twi[e];
                float w2r = twr[2 * e], w2i = twi[2 * e];
                float w3r = twr[3 * e], w3i = twi[3 * e];
                if constexpr (INV) { w1i = -w1i; w2i = -w2i; w3i = -w3i; }
                float r1 = A1r * w1r - A1i * w1i, i1 = A1r * w1i + A1i * w1r;
                float r2 = A2r * w2r - A2i * w2i, i2 = A2r * w2i + A2i * w2r;
                float r3 = A3r * w3r - A3i * w3i, i3 = A3r * w3i + A3i * w3r;
                A1r = r1; A1i = i1; A2r = r2; A2i = i2; A3r = r3; A3i = i3;
            }
            dre[ob]         = A0r; dim_[ob]         = A0i;
            dre[ob + S]     = A1r; dim_[ob + S]     = A1i;
            dre[ob + 2 * S] = A2r; dim_[ob + 2 * S] = A2i;
            dre[ob + 3 * S] = A3r; dim_[ob + 3 * S] = A3i;
        } else {  // R == 3
            float x0r = sre[id],          x0i = sim[id];
            float x1r = sre[NB + id],     x1i = sim[NB + id];
            float x2r = sre[2 * NB + id], x2i = sim[2 * NB + id];
            float tr = x1r + x2r, ti = x1i + x2i;
            float ur = x1r - x2r, ui = x1i - x2i;
            constexpr float C3 = -0.5f;
            constexpr float S3 = INV ? 0.8660254037844386f : -0.8660254037844386f;
            float br = x0r + C3 * tr, bi = x0i + C3 * ti;
            float A0r = x0r + tr, A0i = x0i + ti;
            float A1r = br - S3 * ui, A1i = bi + S3 * ur;  // + i*S3*u
            float A2r = br + S3 * ui, A2i = bi - S3 * ur;  // - i*S3*u
            if constexpr (M > 1) {
                const int e = u * S;
                float w1r = twr[e],     w1i = twi[e];
                float w2r = twr[2 * e], w2i = twi[2 * e];
                if constexpr (INV) { w1i = -w1i; w2i = -w2i; }
                float r1 = A1r * w1r - A1i * w1i, i1 = A1r * w1i + A1i * w1r;
                float r2 = A2r * w2r - A2i * w2i, i2 = A2r * w2i + A2i * w2r;
                A1r = r1; A1i = i1; A2r = r2; A2i = i2;
            }
            dre[ob]         = A0r; dim_[ob]         = A0i;
            dre[ob + S]     = A1r; dim_[ob + S]     = A1i;
            dre[ob + 2 * S] = A2r; dim_[ob + 2 * S] = A2i;
        }
    }
}

// ---------------- kernel 3: FFT -> filter -> modReLU -> iFFT ----------------
__global__ __launch_bounds__(64 * ROWS)
void fftmix_kernel(const float* __restrict__ x, const float* __restrict__ Wb,
                   const float* __restrict__ dW, const float* __restrict__ bias,
                   float* __restrict__ out) {
    __shared__ __align__(16) float twr[DDIM], twi[DDIM];
    __shared__ __align__(16) float Are[ROWS][DDIM], Aim[ROWS][DDIM];
    __shared__ __align__(16) float Bre[ROWS][DDIM], Bim[ROWS][DDIM];

    const int t = threadIdx.x;
    // twiddle table: T[j] = exp(-2*pi*i*j/768)
    for (int j = t; j < DDIM; j += 64 * ROWS) {
        float s, c;
        __sincosf(-(6.283185307179586f / DDIM) * (float)j, &s, &c);
        twr[j] = c; twi[j] = s;
    }

    const int w = t >> 6, lane = t & 63;
    const int row = blockIdx.x * ROWS + w;
    const int b = row >> 12;      // / NSEQ
    const int n = row & (NSEQ - 1);

    float* are = Are[w]; float* aim = Aim[w];
    float* bre = Bre[w]; float* bim = Bim[w];

    // load x row as complex (imag = 0), float4 vectorized
    const float* xr = x + (size_t)row * DDIM;
    #pragma unroll
    for (int q = 0; q < 3; ++q) {
        int c4 = lane + 64 * q;
        float4 v = reinterpret_cast<const float4*>(xr)[c4];
        reinterpret_cast<float4*>(are)[c4] = v;
        reinterpret_cast<float4*>(aim)[c4] = make_float4(0.f, 0.f, 0.f, 0.f);
    }
    __syncthreads();

    // forward FFT: A->B->A->B->A->B
    fft_stage<4, 1, 192, false>(are, aim, bre, bim, twr, twi, lane); __syncthreads();
    fft_stage<4, 4, 48, false>(bre, bim, are, aim, twr, twi, lane); __syncthreads();
    fft_stage<4, 16, 12, false>(are, aim, bre, bim, twr, twi, lane); __syncthreads();
    fft_stage<4, 64, 3, false>(bre, bim, are, aim, twr, twi, lane); __syncthreads();
    fft_stage<3, 256, 1, false>(are, aim, bre, bim, twr, twi, lane); __syncthreads();

    // filter + modReLU in frequency domain (result currently in B)
    const float* wbr = Wb + (size_t)n * DDIM;
    const float* dwr = dW + (size_t)b * DDIM;
    #pragma unroll
    for (int q = 0; q < 12; ++q) {
        int k = lane + 64 * q;
        float fr = bre[k], fi = bim[k];
        float wk = wbr[k] + dwr[k];
        fr *= wk; fi *= wk;
        float mag = sqrtf(fr * fr + fi * fi);
        float mact = fmaxf(mag + bias[k], 0.0f);
        float sc = mact / fmaxf(mag, 1e-8f);
        bre[k] = fr * sc; bim[k] = fi * sc;
    }
    __syncthreads();

    // inverse FFT: B->A->B->A->B->A
    fft_stage<4, 1, 192, true>(bre, bim, are, aim, twr, twi, lane); __syncthreads();
    fft_stage<4, 4, 48, true>(are, aim, bre, bim, twr, twi, lane); __syncthreads();
    fft_stage<4, 16, 12, true>(bre, bim, are, aim, twr, twi, lane); __syncthreads();
    fft_stage<4, 64, 3, true>(are, aim, bre, bim, twr, twi, lane); __syncthreads();
    fft_stage<3, 256, 1, true>(bre, bim, are, aim, twr, twi, lane); __syncthreads();

    // write real part * (1/768)
    float* orow = out + (size_t)row * DDIM;
    constexpr float inv = 1.0f / DDIM;
    #pragma unroll
    for (int q = 0; q < 3; ++q) {
        int c4 = lane + 64 * q;
        float4 v = reinterpret_cast<float4*>(are)[c4];
        v.x *= inv; v.y *= inv; v.z *= inv; v.w *= inv;
        reinterpret_cast<float4*>(orow)[c4] = v;
    }
}

extern "C" void kernel_launch(void* const* d_in, const int* in_sizes, int n_in,
                              void* d_out, int out_size, void* d_ws, size_t ws_size,
                              hipStream_t stream) {
    const float* x    = (const float*)d_in[0];
    const float* Wb   = (const float*)d_in[1];
    const float* bias = (const float*)d_in[2];
    const float* w1   = (const float*)d_in[3];
    const float* b1   = (const float*)d_in[4];
    const float* w2   = (const float*)d_in[5];
    const float* b2   = (const float*)d_in[6];
    float* out = (float*)d_out;

    float* csum = (float*)d_ws;                 // B*D floats
    float* dW   = csum + BDIM * DDIM;           // B*D floats

    hipMemsetAsync(csum, 0, BDIM * DDIM * sizeof(float), stream);
    colsum_kernel<<<BDIM * 3 * 64, 256, 0, stream>>>(x, csum);
    mlp_kernel<<<BDIM, 256, 0, stream>>>(csum, w1, b1, w2, b2, dW);
    fftmix_kernel<<<(BDIM * NSEQ) / ROWS, 64 * ROWS, 0, stream>>>(x, Wb, dW, bias, out);
}

// Round 2
// 238.076 us; speedup vs baseline: 1.1730x; 1.1730x over previous
//
#include <hip/hip_runtime.h>
#include <math.h>

#define BDIM 8
#define NSEQ 4096
#define DDIM 768
#define HDIM 256
#define ROWS 2
#define CH 64

// +1 pad per 32 floats: kills the stride-S Stockham write conflicts
#define SW(a) ((a) + ((a) >> 5))
#define LDSN (DDIM + DDIM / 32)   // 792

// ---------------- kernel 1: column sums over N (float4, atomics) ----------------
__global__ __launch_bounds__(192)
void colsum_kernel(const float* __restrict__ x, float* __restrict__ csum) {
    int blk = blockIdx.x;          // B*CH
    int ch = blk % CH;
    int b  = blk / CH;
    int t  = threadIdx.x;          // 0..191, one float4 column each
    const int nper = NSEQ / CH;    // 64
    const float4* p = reinterpret_cast<const float4*>(
        x + ((size_t)b * NSEQ + (size_t)ch * nper) * DDIM) + t;
    float4 acc = make_float4(0.f, 0.f, 0.f, 0.f);
    #pragma unroll 8
    for (int i = 0; i < nper; ++i) {
        float4 v = p[(size_t)i * (DDIM / 4)];
        acc.x += v.x; acc.y += v.y; acc.z += v.z; acc.w += v.w;
    }
    float* c = csum + b * DDIM + t * 4;
    atomicAdd(c + 0, acc.x);
    atomicAdd(c + 1, acc.y);
    atomicAdd(c + 2, acc.z);
    atomicAdd(c + 3, acc.w);
}

// ---------------- kernel 2: MLP for delta_W ----------------
__global__ __launch_bounds__(256)
void mlp_kernel(const float* __restrict__ csum,
                const float* __restrict__ w1, const float* __restrict__ b1,
                const float* __restrict__ w2, const float* __restrict__ b2,
                float* __restrict__ dW) {
    int b = blockIdx.x;
    int t = threadIdx.x;
    __shared__ float c[DDIM];
    __shared__ float h[HDIM];
    for (int d = t; d < DDIM; d += 256) c[d] = csum[b * DDIM + d] * (1.0f / NSEQ);
    __syncthreads();
    float acc = b1[t];
    #pragma unroll 4
    for (int d = 0; d < DDIM; ++d) acc = fmaf(c[d], w1[d * HDIM + t], acc);
    float x3 = acc * acc * acc;
    float g = 0.5f * acc * (1.0f + tanhf(0.7978845608028654f * (acc + 0.044715f * x3)));
    h[t] = g;
    __syncthreads();
    for (int d = t; d < DDIM; d += 256) {
        float a = b2[d];
        #pragma unroll 4
        for (int j = 0; j < HDIM; ++j) a = fmaf(h[j], w2[j * DDIM + d], a);
        dW[b * DDIM + d] = a;
    }
}

// ---------------- Stockham DIF stage (swizzled LDS) ----------------
template <int R, int S, int M, bool INV>
__device__ __forceinline__ void fft_stage(
    const float* __restrict__ sre, const float* __restrict__ sim,
    float* __restrict__ dre, float* __restrict__ dim_,
    const float* __restrict__ twr, const float* __restrict__ twi, int lane)
{
    constexpr int NB = S * M;  // butterflies = 768/R = read stride
    #pragma unroll
    for (int it = 0; it < NB / 64; ++it) {
        const int id = lane + 64 * it;
        const int u  = id / S;
        const int sg = id - u * S;
        const int ob = u * R * S + sg;
        if constexpr (R == 4) {
            float x0r = sre[SW(id)],          x0i = sim[SW(id)];
            float x1r = sre[SW(NB + id)],     x1i = sim[SW(NB + id)];
            float x2r = sre[SW(2 * NB + id)], x2i = sim[SW(2 * NB + id)];
            float x3r = sre[SW(3 * NB + id)], x3i = sim[SW(3 * NB + id)];
            float t0r = x0r + x2r, t0i = x0i + x2i;
            float t1r = x0r - x2r, t1i = x0i - x2i;
            float t2r = x1r + x3r, t2i = x1i + x3i;
            float t3r = x1r - x3r, t3i = x1i - x3i;
            float A0r = t0r + t2r, A0i = t0i + t2i;
            float A2r = t0r - t2r, A2i = t0i - t2i;
            float A1r, A1i, A3r, A3i;
            if constexpr (!INV) {
                A1r = t1r + t3i; A1i = t1i - t3r;   // t1 - i*t3
                A3r = t1r - t3i; A3i = t1i + t3r;   // t1 + i*t3
            } else {
                A1r = t1r - t3i; A1i = t1i + t3r;
                A3r = t1r + t3i; A3i = t1i - t3r;
            }
            if constexpr (M > 1) {
                const int e = u * S;
                float w1r = twr[e],     w1i = twi[e];
                float w2r = twr[2 * e], w2i = twi[2 * e];
                float w3r = twr[3 * e], w3i = twi[3 * e];
                if constexpr (INV) { w1i = -w1i; w2i = -w2i; w3i = -w3i; }
                float r1 = A1r * w1r - A1i * w1i, i1 = A1r * w1i + A1i * w1r;
                float r2 = A2r * w2r - A2i * w2i, i2 = A2r * w2i + A2i * w2r;
                float r3 = A3r * w3r - A3i * w3i, i3 = A3r * w3i + A3i * w3r;
                A1r = r1; A1i = i1; A2r = r2; A2i = i2; A3r = r3; A3i = i3;
            }
            dre[SW(ob)]         = A0r; dim_[SW(ob)]         = A0i;
            dre[SW(ob + S)]     = A1r; dim_[SW(ob + S)]     = A1i;
            dre[SW(ob + 2 * S)] = A2r; dim_[SW(ob + 2 * S)] = A2i;
            dre[SW(ob + 3 * S)] = A3r; dim_[SW(ob + 3 * S)] = A3i;
        } else {  // R == 3
            float x0r = sre[SW(id)],          x0i = sim[SW(id)];
            float x1r = sre[SW(NB + id)],     x1i = sim[SW(NB + id)];
            float x2r = sre[SW(2 * NB + id)], x2i = sim[SW(2 * NB + id)];
            float tr = x1r + x2r, ti = x1i + x2i;
            float ur = x1r - x2r, ui = x1i - x2i;
            constexpr float C3 = -0.5f;
            constexpr float S3 = INV ? 0.8660254037844386f : -0.8660254037844386f;
            float br = x0r + C3 * tr, bi = x0i + C3 * ti;
            float A0r = x0r + tr, A0i = x0i + ti;
            float A1r = br - S3 * ui, A1i = bi + S3 * ur;
            float A2r = br + S3 * ui, A2i = bi - S3 * ur;
            if constexpr (M > 1) {
                const int e = u * S;
                float w1r = twr[e],     w1i = twi[e];
                float w2r = twr[2 * e], w2i = twi[2 * e];
                if constexpr (INV) { w1i = -w1i; w2i = -w2i; }
                float r1 = A1r * w1r - A1i * w1i, i1 = A1r * w1i + A1i * w1r;
                float r2 = A2r * w2r - A2i * w2i, i2 = A2r * w2i + A2i * w2r;
                A1r = r1; A1i = i1; A2r = r2; A2i = i2;
            }
            dre[SW(ob)]         = A0r; dim_[SW(ob)]         = A0i;
            dre[SW(ob + S)]     = A1r; dim_[SW(ob + S)]     = A1i;
            dre[SW(ob + 2 * S)] = A2r; dim_[SW(ob + 2 * S)] = A2i;
        }
    }
}

// modReLU effective real multiplier: g = w * relu(|w|m + b) / max(|w|m, eps)
__device__ __forceinline__ float geff(float w, float m, float b) {
    float mag = fabsf(w) * m;
    float mact = fmaxf(mag + b, 0.0f);
    return w * (mact / fmaxf(mag, 1e-8f));
}

// ---------------- kernel 3: 2 real rows per complex FFT ----------------
__global__ __launch_bounds__(64 * ROWS)
void fftmix_kernel(const float* __restrict__ x, const float* __restrict__ Wb,
                   const float* __restrict__ dW, const float* __restrict__ bias,
                   float* __restrict__ out) {
    __shared__ float twr[DDIM], twi[DDIM];
    __shared__ float Are[ROWS][LDSN], Aim[ROWS][LDSN];
    __shared__ float Bre[ROWS][LDSN], Bim[ROWS][LDSN];

    const int t = threadIdx.x;
    for (int j = t; j < DDIM; j += 64 * ROWS) {
        float s, c;
        __sincosf(-(6.283185307179586f / DDIM) * (float)j, &s, &c);
        twr[j] = c; twi[j] = s;
    }

    const int w = t >> 6, lane = t & 63;
    const int pair = blockIdx.x * ROWS + w;
    const int r1 = 2 * pair;               // row 1; row 2 = r1+1 (same batch: N even)
    const int b  = r1 >> 12;               // / NSEQ
    const int n1 = r1 & (NSEQ - 1);

    float* are = Are[w]; float* aim = Aim[w];
    float* bre = Bre[w]; float* bim = Bim[w];

    // load z = x[r1] + i * x[r1+1]
    const float* x1 = x + (size_t)r1 * DDIM;
    const float* x2 = x1 + DDIM;
    #pragma unroll
    for (int q = 0; q < 3; ++q) {
        int c4 = lane + 64 * q;
        float4 v1 = reinterpret_cast<const float4*>(x1)[c4];
        float4 v2 = reinterpret_cast<const float4*>(x2)[c4];
        int j = 4 * c4;
        are[SW(j + 0)] = v1.x; are[SW(j + 1)] = v1.y;
        are[SW(j + 2)] = v1.z; are[SW(j + 3)] = v1.w;
        aim[SW(j + 0)] = v2.x; aim[SW(j + 1)] = v2.y;
        aim[SW(j + 2)] = v2.z; aim[SW(j + 3)] = v2.w;
    }
    __syncthreads();

    // forward FFT: A->B->A->B->A->B  (Z in B, natural order)
    fft_stage<4, 1, 192, false>(are, aim, bre, bim, twr, twi, lane); __syncthreads();
    fft_stage<4, 4, 48, false>(bre, bim, are, aim, twr, twi, lane); __syncthreads();
    fft_stage<4, 16, 12, false>(are, aim, bre, bim, twr, twi, lane); __syncthreads();
    fft_stage<4, 64, 3, false>(bre, bim, are, aim, twr, twi, lane); __syncthreads();
    fft_stage<3, 256, 1, false>(are, aim, bre, bim, twr, twi, lane); __syncthreads();

    // unpack 2 spectra, filter+modReLU, repack Hermitian parts (in-place in B)
    {
        const float* wb1 = Wb + (size_t)n1 * DDIM;
        const float* wb2 = wb1 + DDIM;
        const float* dwr = dW + (size_t)b * DDIM;
        auto process = [&](int k) {
            int nk = (k == 0) ? 0 : DDIM - k;
            float Zkr = bre[SW(k)],  Zki = bim[SW(k)];
            float Znr = bre[SW(nk)], Zni = bim[SW(nk)];
            float F1r = 0.5f * (Zkr + Znr), F1i = 0.5f * (Zki - Zni);
            float F2r = 0.5f * (Zki + Zni), F2i = 0.5f * (Znr - Zkr);
            float m1 = sqrtf(F1r * F1r + F1i * F1i);
            float m2 = sqrtf(F2r * F2r + F2i * F2i);
            float dk = dwr[k],  dn = dwr[nk];
            float bk = bias[k], bn = bias[nk];
            float w1k = wb1[k] + dk, w1n = wb1[nk] + dn;
            float w2k = wb2[k] + dk, w2n = wb2[nk] + dn;
            float g1 = 0.5f * (geff(w1k, m1, bk) + geff(w1n, m1, bn));
            float g2 = 0.5f * (geff(w2k, m2, bk) + geff(w2n, m2, bn));
            bre[SW(k)]  = g1 * F1r - g2 * F2i;
            bim[SW(k)]  = g1 * F1i + g2 * F2r;
            bre[SW(nk)] = g1 * F1r + g2 * F2i;
            bim[SW(nk)] = -g1 * F1i + g2 * F2r;
        };
        #pragma unroll
        for (int q = 0; q < 6; ++q) process(lane + 64 * q);
        if (lane == 0) process(384);
    }
    __syncthreads();

    // inverse FFT: B->A->B->A->B->A  (result in A)
    fft_stage<4, 1, 192, true>(bre, bim, are, aim, twr, twi, lane); __syncthreads();
    fft_stage<4, 4, 48, true>(are, aim, bre, bim, twr, twi, lane); __syncthreads();
    fft_stage<4, 16, 12, true>(bre, bim, are, aim, twr, twi, lane); __syncthreads();
    fft_stage<4, 64, 3, true>(are, aim, bre, bim, twr, twi, lane); __syncthreads();
    fft_stage<3, 256, 1, true>(bre, bim, are, aim, twr, twi, lane); __syncthreads();

    // y1 = Re/768 -> row r1 ; y2 = Im/768 -> row r1+1
    float* o1 = out + (size_t)r1 * DDIM;
    float* o2 = o1 + DDIM;
    constexpr float inv = 1.0f / DDIM;
    #pragma unroll
    for (int q = 0; q < 3; ++q) {
        int c4 = lane + 64 * q;
        int j = 4 * c4;
        float4 v1 = make_float4(are[SW(j + 0)], are[SW(j + 1)],
                                are[SW(j + 2)], are[SW(j + 3)]);
        float4 v2 = make_float4(aim[SW(j + 0)], aim[SW(j + 1)],
                                aim[SW(j + 2)], aim[SW(j + 3)]);
        v1.x *= inv; v1.y *= inv; v1.z *= inv; v1.w *= inv;
        v2.x *= inv; v2.y *= inv; v2.z *= inv; v2.w *= inv;
        reinterpret_cast<float4*>(o1)[c4] = v1;
        reinterpret_cast<float4*>(o2)[c4] = v2;
    }
}

extern "C" void kernel_launch(void* const* d_in, const int* in_sizes, int n_in,
                              void* d_out, int out_size, void* d_ws, size_t ws_size,
                              hipStream_t stream) {
    const float* x    = (const float*)d_in[0];
    const float* Wb   = (const float*)d_in[1];
    const float* bias = (const float*)d_in[2];
    const float* w1   = (const float*)d_in[3];
    const float* b1   = (const float*)d_in[4];
    const float* w2   = (const float*)d_in[5];
    const float* b2   = (const float*)d_in[6];
    float* out = (float*)d_out;

    float* csum = (float*)d_ws;                 // B*D floats
    float* dW   = csum + BDIM * DDIM;           // B*D floats

    hipMemsetAsync(csum, 0, BDIM * DDIM * sizeof(float), stream);
    colsum_kernel<<<BDIM * CH, 192, 0, stream>>>(x, csum);
    mlp_kernel<<<BDIM, 256, 0, stream>>>(csum, w1, b1, w2, b2, dW);
    fftmix_kernel<<<(BDIM * NSEQ / 2) / ROWS, 64 * ROWS, 0, stream>>>(x, Wb, dW, bias, out);
}

// Round 4
// 137.926 us; speedup vs baseline: 2.0247x; 1.7261x over previous
//
#include <hip/hip_runtime.h>
#include <math.h>

#define BDIM 8
#define NSEQ 4096
#define DDIM 768
#define HDIM 256
#define ROWS 2
#define CH 64

// +1 pad per 32 floats: kills the stride-S Stockham write conflicts
#define SW(a) ((a) + ((a) >> 5))
#define LDSN (DDIM + DDIM / 32)   // 792

// ---------------- kernel 1: column sums over N (float4, atomics) ----------------
__global__ __launch_bounds__(192)
void colsum_kernel(const float* __restrict__ x, float* __restrict__ csum) {
    int blk = blockIdx.x;          // B*CH
    int ch = blk % CH;
    int b  = blk / CH;
    int t  = threadIdx.x;          // 0..191, one float4 column each
    const int nper = NSEQ / CH;    // 64
    const float4* p = reinterpret_cast<const float4*>(
        x + ((size_t)b * NSEQ + (size_t)ch * nper) * DDIM) + t;
    float4 acc = make_float4(0.f, 0.f, 0.f, 0.f);
    #pragma unroll 8
    for (int i = 0; i < nper; ++i) {
        float4 v = p[(size_t)i * (DDIM / 4)];
        acc.x += v.x; acc.y += v.y; acc.z += v.z; acc.w += v.w;
    }
    float* c = csum + b * DDIM + t * 4;
    atomicAdd(c + 0, acc.x);
    atomicAdd(c + 1, acc.y);
    atomicAdd(c + 2, acc.z);
    atomicAdd(c + 3, acc.w);
}

// ---------------- kernel 2a: h = gelu(c @ w1 + b1), one block per (b,hh) ----------------
__global__ __launch_bounds__(64)
void mlp_h_kernel(const float* __restrict__ csum, const float* __restrict__ w1,
                  const float* __restrict__ b1, float* __restrict__ h) {
    const int blk = blockIdx.x;
    const int hh = blk & (HDIM - 1);
    const int b  = blk >> 8;
    const int l  = threadIdx.x;
    const float* c = csum + b * DDIM;
    const float* w = w1 + hh;
    float acc = 0.f;
    #pragma unroll
    for (int j = 0; j < 12; ++j) {
        int d = l * 12 + j;
        acc = fmaf(c[d], w[(size_t)d * HDIM], acc);
    }
    #pragma unroll
    for (int off = 32; off; off >>= 1) acc += __shfl_down(acc, off);
    if (l == 0) {
        float a = acc * (1.0f / NSEQ) + b1[hh];
        float x3 = a * a * a;
        float g = 0.5f * a * (1.0f + tanhf(0.7978845608028654f * (a + 0.044715f * x3)));
        h[b * HDIM + hh] = g;
    }
}

// ---------------- kernel 2b: dW += h @ w2 (partial j-chunks, atomics) ----------------
// grid: b * 4 j-chunks * 12 d-chunks; block 64 = 64 consecutive d's
__global__ __launch_bounds__(64)
void mlp_dw_kernel(const float* __restrict__ h, const float* __restrict__ w2,
                   float* __restrict__ dW) {
    const int blk = blockIdx.x;
    const int dc = blk % 12;
    const int jc = (blk / 12) & 3;
    const int b  = blk / 48;
    const int l  = threadIdx.x;
    __shared__ float hs[64];
    hs[l] = h[b * HDIM + jc * 64 + l];
    __syncthreads();
    const int d = dc * 64 + l;
    const float* w = w2 + (size_t)(jc * 64) * DDIM + d;
    float acc = 0.f;
    #pragma unroll 8
    for (int j = 0; j < 64; ++j) acc = fmaf(hs[j], w[(size_t)j * DDIM], acc);
    atomicAdd(&dW[b * DDIM + d], acc);
}

// ---------------- Stockham DIF stage (swizzled LDS) ----------------
template <int R, int S, int M, bool INV>
__device__ __forceinline__ void fft_stage(
    const float* __restrict__ sre, const float* __restrict__ sim,
    float* __restrict__ dre, float* __restrict__ dim_,
    const float* __restrict__ twr, const float* __restrict__ twi, int lane)
{
    constexpr int NB = S * M;  // butterflies = 768/R = read stride
    #pragma unroll
    for (int it = 0; it < NB / 64; ++it) {
        const int id = lane + 64 * it;
        const int u  = id / S;
        const int sg = id - u * S;
        const int ob = u * R * S + sg;
        if constexpr (R == 4) {
            float x0r = sre[SW(id)],          x0i = sim[SW(id)];
            float x1r = sre[SW(NB + id)],     x1i = sim[SW(NB + id)];
            float x2r = sre[SW(2 * NB + id)], x2i = sim[SW(2 * NB + id)];
            float x3r = sre[SW(3 * NB + id)], x3i = sim[SW(3 * NB + id)];
            float t0r = x0r + x2r, t0i = x0i + x2i;
            float t1r = x0r - x2r, t1i = x0i - x2i;
            float t2r = x1r + x3r, t2i = x1i + x3i;
            float t3r = x1r - x3r, t3i = x1i - x3i;
            float A0r = t0r + t2r, A0i = t0i + t2i;
            float A2r = t0r - t2r, A2i = t0i - t2i;
            float A1r, A1i, A3r, A3i;
            if constexpr (!INV) {
                A1r = t1r + t3i; A1i = t1i - t3r;   // t1 - i*t3
                A3r = t1r - t3i; A3i = t1i + t3r;   // t1 + i*t3
            } else {
                A1r = t1r - t3i; A1i = t1i + t3r;
                A3r = t1r + t3i; A3i = t1i - t3r;
            }
            if constexpr (M > 1) {
                const int e = u * S;
                float w1r = twr[e],     w1i = twi[e];
                float w2r = twr[2 * e], w2i = twi[2 * e];
                float w3r = twr[3 * e], w3i = twi[3 * e];
                if constexpr (INV) { w1i = -w1i; w2i = -w2i; w3i = -w3i; }
                float r1 = A1r * w1r - A1i * w1i, i1 = A1r * w1i + A1i * w1r;
                float r2 = A2r * w2r - A2i * w2i, i2 = A2r * w2i + A2i * w2r;
                float r3 = A3r * w3r - A3i * w3i, i3 = A3r * w3i + A3i * w3r;
                A1r = r1; A1i = i1; A2r = r2; A2i = i2; A3r = r3; A3i = i3;
            }
            dre[SW(ob)]         = A0r; dim_[SW(ob)]         = A0i;
            dre[SW(ob + S)]     = A1r; dim_[SW(ob + S)]     = A1i;
            dre[SW(ob + 2 * S)] = A2r; dim_[SW(ob + 2 * S)] = A2i;
            dre[SW(ob + 3 * S)] = A3r; dim_[SW(ob + 3 * S)] = A3i;
        } else {  // R == 3
            float x0r = sre[SW(id)],          x0i = sim[SW(id)];
            float x1r = sre[SW(NB + id)],     x1i = sim[SW(NB + id)];
            float x2r = sre[SW(2 * NB + id)], x2i = sim[SW(2 * NB + id)];
            float tr = x1r + x2r, ti = x1i + x2i;
            float ur = x1r - x2r, ui = x1i - x2i;
            constexpr float C3 = -0.5f;
            constexpr float S3 = INV ? 0.8660254037844386f : -0.8660254037844386f;
            float br = x0r + C3 * tr, bi = x0i + C3 * ti;
            float A0r = x0r + tr, A0i = x0i + ti;
            float A1r = br - S3 * ui, A1i = bi + S3 * ur;
            float A2r = br + S3 * ui, A2i = bi - S3 * ur;
            if constexpr (M > 1) {
                const int e = u * S;
                float w1r = twr[e],     w1i = twi[e];
                float w2r = twr[2 * e], w2i = twi[2 * e];
                if constexpr (INV) { w1i = -w1i; w2i = -w2i; }
                float r1 = A1r * w1r - A1i * w1i, i1 = A1r * w1i + A1i * w1r;
                float r2 = A2r * w2r - A2i * w2i, i2 = A2r * w2i + A2i * w2r;
                A1r = r1; A1i = i1; A2r = r2; A2i = i2;
            }
            dre[SW(ob)]         = A0r; dim_[SW(ob)]         = A0i;
            dre[SW(ob + S)]     = A1r; dim_[SW(ob + S)]     = A1i;
            dre[SW(ob + 2 * S)] = A2r; dim_[SW(ob + 2 * S)] = A2i;
        }
    }
}

// modReLU effective real multiplier: g = w * relu(|w|m + b) / max(|w|m, eps)
__device__ __forceinline__ float geff(float w, float m, float b) {
    float mag = fabsf(w) * m;
    float mact = fmaxf(mag + b, 0.0f);
    return w * (mact / fmaxf(mag, 1e-8f));
}

// ---------------- kernel 3: 2 real rows per complex FFT ----------------
__global__ __launch_bounds__(64 * ROWS)
void fftmix_kernel(const float* __restrict__ x, const float* __restrict__ Wb,
                   const float* __restrict__ dW, const float* __restrict__ bias,
                   const float* __restrict__ b2, float* __restrict__ out) {
    __shared__ float twr[DDIM], twi[DDIM];
    __shared__ float Are[ROWS][LDSN], Aim[ROWS][LDSN];
    __shared__ float Bre[ROWS][LDSN], Bim[ROWS][LDSN];

    const int t = threadIdx.x;
    for (int j = t; j < DDIM; j += 64 * ROWS) {
        float s, c;
        __sincosf(-(6.283185307179586f / DDIM) * (float)j, &s, &c);
        twr[j] = c; twi[j] = s;
    }

    const int w = t >> 6, lane = t & 63;
    const int pair = blockIdx.x * ROWS + w;
    const int r1 = 2 * pair;               // row 1; row 2 = r1+1 (same batch: N even)
    const int b  = r1 >> 12;               // / NSEQ
    const int n1 = r1 & (NSEQ - 1);

    float* are = Are[w]; float* aim = Aim[w];
    float* bre = Bre[w]; float* bim = Bim[w];

    // load z = x[r1] + i * x[r1+1]
    const float* x1 = x + (size_t)r1 * DDIM;
    const float* x2 = x1 + DDIM;
    #pragma unroll
    for (int q = 0; q < 3; ++q) {
        int c4 = lane + 64 * q;
        float4 v1 = reinterpret_cast<const float4*>(x1)[c4];
        float4 v2 = reinterpret_cast<const float4*>(x2)[c4];
        int j = 4 * c4;
        are[SW(j + 0)] = v1.x; are[SW(j + 1)] = v1.y;
        are[SW(j + 2)] = v1.z; are[SW(j + 3)] = v1.w;
        aim[SW(j + 0)] = v2.x; aim[SW(j + 1)] = v2.y;
        aim[SW(j + 2)] = v2.z; aim[SW(j + 3)] = v2.w;
    }
    __syncthreads();

    // forward FFT: A->B->A->B->A->B  (Z in B, natural order)
    fft_stage<4, 1, 192, false>(are, aim, bre, bim, twr, twi, lane); __syncthreads();
    fft_stage<4, 4, 48, false>(bre, bim, are, aim, twr, twi, lane); __syncthreads();
    fft_stage<4, 16, 12, false>(are, aim, bre, bim, twr, twi, lane); __syncthreads();
    fft_stage<4, 64, 3, false>(bre, bim, are, aim, twr, twi, lane); __syncthreads();
    fft_stage<3, 256, 1, false>(are, aim, bre, bim, twr, twi, lane); __syncthreads();

    // unpack 2 spectra, filter+modReLU, repack Hermitian parts (in-place in B)
    {
        const float* wb1 = Wb + (size_t)n1 * DDIM;
        const float* wb2 = wb1 + DDIM;
        const float* dwr = dW + (size_t)b * DDIM;
        auto process = [&](int k) {
            int nk = (k == 0) ? 0 : DDIM - k;
            float Zkr = bre[SW(k)],  Zki = bim[SW(k)];
            float Znr = bre[SW(nk)], Zni = bim[SW(nk)];
            float F1r = 0.5f * (Zkr + Znr), F1i = 0.5f * (Zki - Zni);
            float F2r = 0.5f * (Zki + Zni), F2i = 0.5f * (Znr - Zkr);
            float m1 = sqrtf(F1r * F1r + F1i * F1i);
            float m2 = sqrtf(F2r * F2r + F2i * F2i);
            float dk = dwr[k] + b2[k],  dn = dwr[nk] + b2[nk];
            float bk = bias[k], bn = bias[nk];
            float w1k = wb1[k] + dk, w1n = wb1[nk] + dn;
            float w2k = wb2[k] + dk, w2n = wb2[nk] + dn;
            float g1 = 0.5f * (geff(w1k, m1, bk) + geff(w1n, m1, bn));
            float g2 = 0.5f * (geff(w2k, m2, bk) + geff(w2n, m2, bn));
            bre[SW(k)]  = g1 * F1r - g2 * F2i;
            bim[SW(k)]  = g1 * F1i + g2 * F2r;
            bre[SW(nk)] = g1 * F1r + g2 * F2i;
            bim[SW(nk)] = -g1 * F1i + g2 * F2r;
        };
        #pragma unroll
        for (int q = 0; q < 6; ++q) process(lane + 64 * q);
        if (lane == 0) process(384);
    }
    __syncthreads();

    // inverse FFT: B->A->B->A->B->A  (result in A)
    fft_stage<4, 1, 192, true>(bre, bim, are, aim, twr, twi, lane); __syncthreads();
    fft_stage<4, 4, 48, true>(are, aim, bre, bim, twr, twi, lane); __syncthreads();
    fft_stage<4, 16, 12, true>(bre, bim, are, aim, twr, twi, lane); __syncthreads();
    fft_stage<4, 64, 3, true>(are, aim, bre, bim, twr, twi, lane); __syncthreads();
    fft_stage<3, 256, 1, true>(bre, bim, are, aim, twr, twi, lane); __syncthreads();

    // y1 = Re/768 -> row r1 ; y2 = Im/768 -> row r1+1
    float* o1 = out + (size_t)r1 * DDIM;
    float* o2 = o1 + DDIM;
    constexpr float inv = 1.0f / DDIM;
    #pragma unroll
    for (int q = 0; q < 3; ++q) {
        int c4 = lane + 64 * q;
        int j = 4 * c4;
        float4 v1 = make_float4(are[SW(j + 0)], are[SW(j + 1)],
                                are[SW(j + 2)], are[SW(j + 3)]);
        float4 v2 = make_float4(aim[SW(j + 0)], aim[SW(j + 1)],
                                aim[SW(j + 2)], aim[SW(j + 3)]);
        v1.x *= inv; v1.y *= inv; v1.z *= inv; v1.w *= inv;
        v2.x *= inv; v2.y *= inv; v2.z *= inv; v2.w *= inv;
        reinterpret_cast<float4*>(o1)[c4] = v1;
        reinterpret_cast<float4*>(o2)[c4] = v2;
    }
}

extern "C" void kernel_launch(void* const* d_in, const int* in_sizes, int n_in,
                              void* d_out, int out_size, void* d_ws, size_t ws_size,
                              hipStream_t stream) {
    const float* x    = (const float*)d_in[0];
    const float* Wb   = (const float*)d_in[1];
    const float* bias = (const float*)d_in[2];
    const float* w1   = (const float*)d_in[3];
    const float* b1   = (const float*)d_in[4];
    const float* w2   = (const float*)d_in[5];
    const float* b2   = (const float*)d_in[6];
    float* out = (float*)d_out;

    float* csum = (float*)d_ws;                 // B*D floats
    float* dW   = csum + BDIM * DDIM;           // B*D floats (h@w2 partials; b2 folded into fftmix)
    float* h    = dW + BDIM * DDIM;             // B*H floats

    hipMemsetAsync(d_ws, 0, 2 * BDIM * DDIM * sizeof(float), stream);
    colsum_kernel<<<BDIM * CH, 192, 0, stream>>>(x, csum);
    mlp_h_kernel<<<BDIM * HDIM, 64, 0, stream>>>(csum, w1, b1, h);
    mlp_dw_kernel<<<BDIM * 4 * 12, 64, 0, stream>>>(h, w2, dW);
    fftmix_kernel<<<(BDIM * NSEQ / 2) / ROWS, 64 * ROWS, 0, stream>>>(x, Wb, dW, bias, b2, out);
}